// Round 7
// baseline (319.431 us; speedup 1.0000x reference)
//
#include <hip/hip_runtime.h>
#include <hip/hip_bf16.h>

#define N_NODES 50000
#define N_EDGES 600000
#define DIM 128
#define N_GRAPHS 64
#define CAP 64            // padded CSR row capacity (mean deg 12; P(deg>=64)~0)
#define CAP_SHIFT 6

typedef __bf16 bf16x8 __attribute__((ext_vector_type(8)));
typedef float f32x4 __attribute__((ext_vector_type(4)));
typedef float f32x2 __attribute__((ext_vector_type(2)));

// round-to-nearest-even fp32 -> bf16 (as ushort)
__device__ __forceinline__ unsigned short f2bf(float f) {
    unsigned int u = __float_as_uint(f);
    u += 0x7FFFu + ((u >> 16) & 1u);
    return (unsigned short)(u >> 16);
}
__device__ __forceinline__ unsigned char f2fp8(float v) {
    return (unsigned char)(__builtin_amdgcn_cvt_pk_fp8_f32(v, v, 0, false) & 0xFF);
}

// async gather: 64 lanes x 16B from PER-LANE global addresses -> contiguous
// 1024B at wave-uniform LDS base (+lane*16). Zero VGPR cost, vmcnt-tracked.
__device__ __forceinline__ void gll16(const void* g, void* l) {
    __builtin_amdgcn_global_load_lds(
        (__attribute__((address_space(1))) unsigned int*)g,
        (__attribute__((address_space(3))) unsigned int*)l, 16, 0, 0);
}

// ---------------------------------------------------------------------------
// zero accumulators + conv_W -> bf16 transposed WT[l][n][k]
// ---------------------------------------------------------------------------
__global__ __launch_bounds__(256) void zero_wt_kernel(int* __restrict__ deg_out,
                                                      int* __restrict__ cnt_in,
                                                      float* __restrict__ gsum,
                                                      float* __restrict__ gcnt,
                                                      const float* __restrict__ w,
                                                      unsigned short* __restrict__ wt) {
    int i = blockIdx.x * blockDim.x + threadIdx.x;
    if (i < N_NODES) { deg_out[i] = 0; cnt_in[i] = 0; }
    if (i < N_GRAPHS * DIM) gsum[i] = 0.f;
    if (i < N_GRAPHS) gcnt[i] = 0.f;
    if (i < 4 * DIM * DIM) {
        int l = i >> 14;           // layer
        int j = i & 16383;
        int k = j >> 7;
        int n = j & 127;
        wt[(l << 14) + n * DIM + k] = f2bf(w[i]);
    }
}

// ---------------------------------------------------------------------------
// fused CSR build: one edge per thread (measured-best form; 4-edge ILP
// variant collapsed occupancy 60%->20% and regressed).
// ---------------------------------------------------------------------------
__global__ __launch_bounds__(256) void build_kernel(const int* __restrict__ src,
                                                    const int* __restrict__ dst,
                                                    int* __restrict__ deg_out,
                                                    int* __restrict__ cnt_in,
                                                    unsigned short* __restrict__ slots, int ne) {
    int e = blockIdx.x * blockDim.x + threadIdx.x;
    if (e < ne) {
        int s = src[e];
        int d = dst[e];
        atomicAdd(&deg_out[s], 1);
        int p = atomicAdd(&cnt_in[d], 1);
        if (p < CAP) slots[(d << CAP_SHIFT) + p] = (unsigned short)s;
    }
}

// ---------------------------------------------------------------------------
// xs(fp8) = e4m3( x * rsqrt(max(deg_out,1)) )   (norm_src computed inline)
// ---------------------------------------------------------------------------
__global__ __launch_bounds__(256) void scale_x_kernel(const float* __restrict__ x,
                                                      const int* __restrict__ deg_out,
                                                      unsigned char* __restrict__ xs) {
    int i = blockIdx.x * blockDim.x + threadIdx.x;     // 8-float chunk index
    if (i >= N_NODES * (DIM / 8)) return;
    int row = i >> 4;                                   // 16 chunks per row
    float ns = __frsqrt_rn(fmaxf((float)deg_out[row], 1.0f));
    const float4* px = (const float4*)(x + (size_t)i * 8);
    float4 v0 = px[0], v1 = px[1];
    unsigned lo = 0, hi = 0;
    lo = __builtin_amdgcn_cvt_pk_fp8_f32(v0.x * ns, v0.y * ns, lo, false);
    lo = __builtin_amdgcn_cvt_pk_fp8_f32(v0.z * ns, v0.w * ns, lo, true);
    hi = __builtin_amdgcn_cvt_pk_fp8_f32(v1.x * ns, v1.y * ns, hi, false);
    hi = __builtin_amdgcn_cvt_pk_fp8_f32(v1.z * ns, v1.w * ns, hi, true);
    uint2 o = {lo, hi};
    *(uint2*)(xs + (size_t)i * 8) = o;
}

// ---------------------------------------------------------------------------
// FUSED conv, async-DMA gather:
// Phase 1 (spmm): per wave, 4 nodes. Edges 0..15 of each node are staged
//   into LDS via global_load_lds gathers (one instr = 8 full fp8 rows,
//   per-lane random global src, zero VGPR). Up to 8 async instrs in flight
//   per wave before a single vmcnt(0) -> latency is amortized across ~100s
//   of outstanding lines per CU instead of ~14 (the round-6 VGPR-staged
//   ceiling). Accumulation then reads LDS with the EXACT round-6 lane
//   geometry and summation order (absmax-preserving). Edge lanes >= cnt are
//   clamped to row 0 (L1-hot, ~free). Residual edges (deg>16, ~10% of
//   nodes) keep the old direct-global path.
// Phase 2 (gemm): unchanged MFMA + epilogue (fp8 store or mean-pool).
// ---------------------------------------------------------------------------
#define LDS_STRIDE 136   // ushorts per row (128 + 8 pad = 272B; 272 % 16 == 0)
__global__ __launch_bounds__(256) void conv_fused_kernel(const int* __restrict__ cnt_in,
                                                         const unsigned short* __restrict__ slots,
                                                         const unsigned char* __restrict__ h8,
                                                         const unsigned short* __restrict__ WT,
                                                         const float* __restrict__ bias,
                                                         unsigned char* __restrict__ C8,
                                                         const int* __restrict__ deg_out,   // non-null: epilogue *rsqrt(deg_out)
                                                         const int* __restrict__ graph_id,  // non-null: pool epilogue
                                                         float* __restrict__ gsum,
                                                         float* __restrict__ gcnt,
                                                         int do_relu) {
    __shared__ unsigned char stage[4][4][2048];        // [wave][node][16 rows x 128B]
    __shared__ unsigned short tileA[16][LDS_STRIDE];
    int wave = threadIdx.x >> 6;
    int lane = threadIdx.x & 63;
    int slot = lane >> 4;          // 0..3: row group within accumulate pass
    int sub  = lane & 15;          // 8-byte chunk of the 128-byte fp8 row
    int r0 = blockIdx.x * 16;
    int nb = r0 + wave * 4;        // first of this wave's 4 nodes

    // wave-uniform node degrees (one 16B load)
    int4 c4 = *(const int4*)(cnt_in + nb);
    int craw[4], cnt[4];
    #pragma unroll
    for (int nn = 0; nn < 4; nn++) {
        craw[nn] = (&c4.x)[nn];
        cnt[nn] = craw[nn] > CAP ? CAP : craw[nn];
    }

    // ---- stage edges 0..15 of all 4 nodes via async DMA gathers ----
    {
        int er = lane >> 3;            // edge row 0..7 within a staging instr
        int cb = (lane & 7) * 16;      // 16B chunk within the 128B row
        #pragma unroll
        for (int nn = 0; nn < 4; nn++) {
            if (cnt[nn] > 0) {
                int beg = (nb + nn) << CAP_SHIFT;
                int s0 = (int)slots[beg + er];
                if (er >= cnt[nn]) s0 = 0;             // clamp: row 0, L1-hot
                gll16(h8 + (size_t)s0 * DIM + cb, &stage[wave][nn][0]);
                if (cnt[nn] > 8) {
                    int s1 = (int)slots[beg + 8 + er];
                    if (8 + er >= cnt[nn]) s1 = 0;
                    gll16(h8 + (size_t)s1 * DIM + cb, &stage[wave][nn][1024]);
                }
            }
        }
    }
    asm volatile("s_waitcnt vmcnt(0)" ::: "memory");   // wave-level drain

    // ---- accumulate (round-6-identical order) ----
    const unsigned char* hp = h8 + sub * 8;
    float a[4][8] = {};

    // first chunk (edges 0..15) from LDS stage
    #pragma unroll
    for (int nn = 0; nn < 4; nn++) {
        const unsigned char* st = &stage[wave][nn][0];
        #pragma unroll
        for (int j = 0; j < 4; j++) {
            int e = slot + 4 * j;
            if (e < cnt[nn]) {
                uint2 v = *(const uint2*)(st + e * 128 + sub * 8);
                f32x2 p0 = __builtin_amdgcn_cvt_pk_f32_fp8(v.x, false);
                f32x2 p1 = __builtin_amdgcn_cvt_pk_f32_fp8(v.x, true);
                f32x2 p2 = __builtin_amdgcn_cvt_pk_f32_fp8(v.y, false);
                f32x2 p3 = __builtin_amdgcn_cvt_pk_f32_fp8(v.y, true);
                a[nn][0] += p0[0]; a[nn][1] += p0[1]; a[nn][2] += p1[0]; a[nn][3] += p1[1];
                a[nn][4] += p2[0]; a[nn][5] += p2[1]; a[nn][6] += p3[0]; a[nn][7] += p3[1];
            }
        }
    }

    // residual chunks (deg > 16; wave-uniform branch, ~10% of nodes): global
    #pragma unroll
    for (int nn = 0; nn < 4; nn++) {
        for (int base = 16; base < cnt[nn]; base += 16) {
            int idx = (int)slots[((nb + nn) << CAP_SHIFT) + base + sub];
            #pragma unroll
            for (int j = 0; j < 4; j++) {
                int e = base + slot + 4 * j;
                int s = __shfl(idx, slot + 4 * j);
                if (e < cnt[nn]) {
                    uint2 v = *(const uint2*)(hp + (size_t)s * DIM);
                    f32x2 p0 = __builtin_amdgcn_cvt_pk_f32_fp8(v.x, false);
                    f32x2 p1 = __builtin_amdgcn_cvt_pk_f32_fp8(v.x, true);
                    f32x2 p2 = __builtin_amdgcn_cvt_pk_f32_fp8(v.y, false);
                    f32x2 p3 = __builtin_amdgcn_cvt_pk_f32_fp8(v.y, true);
                    a[nn][0] += p0[0]; a[nn][1] += p0[1]; a[nn][2] += p1[0]; a[nn][3] += p1[1];
                    a[nn][4] += p2[0]; a[nn][5] += p2[1]; a[nn][6] += p3[0]; a[nn][7] += p3[1];
                }
            }
        }
    }

    // reduce across the 4 row-groups + store finished bf16 rows (round-0 tree)
    #pragma unroll
    for (int nn = 0; nn < 4; nn++) {
        #pragma unroll
        for (int k = 0; k < 8; k++) {
            a[nn][k] += __shfl_xor(a[nn][k], 16);
            a[nn][k] += __shfl_xor(a[nn][k], 32);
        }
        if (slot == 0) {
            float nd = __frsqrt_rn(fmaxf((float)craw[nn], 1.0f));   // norm_dst inline
            uint4 o;
            o.x = (unsigned)f2bf(a[nn][0] * nd) | ((unsigned)f2bf(a[nn][1] * nd) << 16);
            o.y = (unsigned)f2bf(a[nn][2] * nd) | ((unsigned)f2bf(a[nn][3] * nd) << 16);
            o.z = (unsigned)f2bf(a[nn][4] * nd) | ((unsigned)f2bf(a[nn][5] * nd) << 16);
            o.w = (unsigned)f2bf(a[nn][6] * nd) | ((unsigned)f2bf(a[nn][7] * nd) << 16);
            *(uint4*)&tileA[wave * 4 + nn][sub * 8] = o;
        }
    }
    __syncthreads();

    // ---- phase 2: C[16 x 32-col slice] via MFMA ----
    int quad = lane >> 4;
    int l15 = lane & 15;
    int ct0 = wave * 2;            // two 16-col tiles per wave

    f32x4 acc[2];
    #pragma unroll
    for (int t = 0; t < 2; t++) {
        float bv = bias[(ct0 + t) * 16 + l15];
        acc[t] = (f32x4){bv, bv, bv, bv};
    }

    #pragma unroll
    for (int ks = 0; ks < 4; ks++) {
        bf16x8 af = *(const bf16x8*)&tileA[l15][ks * 32 + quad * 8];
        #pragma unroll
        for (int t = 0; t < 2; t++) {
            bf16x8 bf = *(const bf16x8*)(WT + (size_t)((ct0 + t) * 16 + l15) * DIM + ks * 32 + quad * 8);
            acc[t] = __builtin_amdgcn_mfma_f32_16x16x32_bf16(af, bf, acc[t], 0, 0, 0);
        }
    }

    if (graph_id == nullptr) {
        // conv0..2 epilogue: relu + inline norm_src scale, fp8 store
        #pragma unroll
        for (int reg = 0; reg < 4; reg++) {
            int r = r0 + quad * 4 + reg;
            float rs = __frsqrt_rn(fmaxf((float)deg_out[r], 1.0f));
            #pragma unroll
            for (int t = 0; t < 2; t++) {
                float v = acc[t][reg];
                if (do_relu) v = fmaxf(v, 0.f);
                v *= rs;
                C8[(size_t)r * DIM + (ct0 + t) * 16 + l15] = f2fp8(v);
            }
        }
    } else {
        // conv3 epilogue: mean-pool directly (no C store)
        int g0 = graph_id[r0];
        int g15 = graph_id[r0 + 15];
        if (g0 == g15) {
            // fast path: whole block in one graph
            #pragma unroll
            for (int t = 0; t < 2; t++) {
                float s = acc[t][0] + acc[t][1] + acc[t][2] + acc[t][3];  // 4 rows
                s += __shfl_xor(s, 16);
                s += __shfl_xor(s, 32);        // all 16 rows
                if (quad == 0)
                    atomicAdd(&gsum[g0 * DIM + (ct0 + t) * 16 + l15], s);
            }
            if (threadIdx.x == 0) atomicAdd(&gcnt[g0], 16.0f);
        } else {
            // slow path: per-row atomics (block spans a graph boundary)
            #pragma unroll
            for (int reg = 0; reg < 4; reg++) {
                int r = r0 + quad * 4 + reg;
                int g = graph_id[r];
                #pragma unroll
                for (int t = 0; t < 2; t++)
                    atomicAdd(&gsum[g * DIM + (ct0 + t) * 16 + l15], acc[t][reg]);
            }
            if (threadIdx.x < 16)
                atomicAdd(&gcnt[graph_id[r0 + threadIdx.x]], 1.0f);
        }
    }
}

// ---------------------------------------------------------------------------
// FFNN head: one block per graph (fp32)
// ---------------------------------------------------------------------------
__global__ __launch_bounds__(128) void mlp_kernel(const float* __restrict__ gsum,
                                                  const float* __restrict__ gcnt,
                                                  const float* __restrict__ ffnn_W,
                                                  const float* __restrict__ ffnn_b,
                                                  const float* __restrict__ out_W,
                                                  const float* __restrict__ out_b,
                                                  float* __restrict__ out) {
    __shared__ float buf[DIM];
    __shared__ float red[DIM];
    int g = blockIdx.x;
    int t = threadIdx.x;
    float cnt = fmaxf(gcnt[g], 1.0f);
    buf[t] = gsum[g * DIM + t] / cnt;
    __syncthreads();
    for (int l = 0; l < 3; l++) {
        const float* W = ffnn_W + (size_t)l * DIM * DIM;
        float s = ffnn_b[l * DIM + t];
        for (int k = 0; k < DIM; k++) s += buf[k] * W[k * DIM + t];
        __syncthreads();
        buf[t] = fmaxf(s, 0.0f);
        __syncthreads();
    }
    float p = buf[t] * out_W[t];
    red[t] = p;
    __syncthreads();
    for (int off = 64; off > 0; off >>= 1) {
        if (t < off) red[t] += red[t + off];
        __syncthreads();
    }
    if (t == 0) out[g] = 1.0f / (1.0f + expf(-(red[0] + out_b[0])));
}

// ---------------------------------------------------------------------------
// launch (8 dispatches)
// ---------------------------------------------------------------------------
extern "C" void kernel_launch(void* const* d_in, const int* in_sizes, int n_in,
                              void* d_out, int out_size, void* d_ws, size_t ws_size,
                              hipStream_t stream) {
    const float* x        = (const float*)d_in[0];
    const int*   src      = (const int*)d_in[1];
    const int*   dst      = (const int*)d_in[2];
    const int*   graph_id = (const int*)d_in[3];
    const float* conv_W   = (const float*)d_in[4];
    const float* conv_b   = (const float*)d_in[5];
    const float* ffnn_W   = (const float*)d_in[6];
    const float* ffnn_b   = (const float*)d_in[7];
    const float* out_W    = (const float*)d_in[8];
    const float* out_b    = (const float*)d_in[9];
    float* out = (float*)d_out;

    char* w = (char*)d_ws;
    auto alloc = [&](size_t bytes) -> void* {
        void* p = (void*)w;
        w += (bytes + 255) & ~(size_t)255;
        return p;
    };
    int*            deg_out_i = (int*)alloc(N_NODES * sizeof(int));
    int*            cnt_in    = (int*)alloc(N_NODES * sizeof(int));
    unsigned short* slots     = (unsigned short*)alloc((size_t)N_NODES * CAP * sizeof(unsigned short));
    unsigned char*  h8a  = (unsigned char*)alloc((size_t)N_NODES * DIM);          // fp8 ping
    unsigned char*  h8b  = (unsigned char*)alloc((size_t)N_NODES * DIM);          // fp8 pong
    unsigned short* wbfT = (unsigned short*)alloc(4 * DIM * DIM * sizeof(unsigned short));
    float* gsum      = (float*)alloc(N_GRAPHS * DIM * sizeof(float));
    float* gcnt      = (float*)alloc(N_GRAPHS * sizeof(float));

    // zero + WT transpose (256 blocks to cover 4*128*128 = 65536)
    zero_wt_kernel<<<(4 * DIM * DIM + 255) / 256, 256, 0, stream>>>(deg_out_i, cnt_in, gsum, gcnt, conv_W, wbfT);
    build_kernel<<<(N_EDGES + 255) / 256, 256, 0, stream>>>(src, dst, deg_out_i, cnt_in, slots, N_EDGES);
    scale_x_kernel<<<(N_NODES * (DIM / 8) + 255) / 256, 256, 0, stream>>>(x, deg_out_i, h8a);

    const int conv_blocks = N_NODES / 16;   // 3125

    // conv0..2: fused spmm+gemm, fp8 out (relu + inline norm_src)
    conv_fused_kernel<<<conv_blocks, 256, 0, stream>>>(cnt_in, slots, h8a,
        wbfT + 0 * DIM * DIM, conv_b + 0 * DIM, h8b, deg_out_i,
        (const int*)nullptr, (float*)nullptr, (float*)nullptr, 1);
    conv_fused_kernel<<<conv_blocks, 256, 0, stream>>>(cnt_in, slots, h8b,
        wbfT + 1 * DIM * DIM, conv_b + 1 * DIM, h8a, deg_out_i,
        (const int*)nullptr, (float*)nullptr, (float*)nullptr, 1);
    conv_fused_kernel<<<conv_blocks, 256, 0, stream>>>(cnt_in, slots, h8a,
        wbfT + 2 * DIM * DIM, conv_b + 2 * DIM, h8b, deg_out_i,
        (const int*)nullptr, (float*)nullptr, (float*)nullptr, 1);
    // conv3: no relu, no scale, pooled epilogue (no C store)
    conv_fused_kernel<<<conv_blocks, 256, 0, stream>>>(cnt_in, slots, h8b,
        wbfT + 3 * DIM * DIM, conv_b + 3 * DIM, (unsigned char*)nullptr, (const int*)nullptr,
        graph_id, gsum, gcnt, 0);

    // head
    mlp_kernel<<<N_GRAPHS, 128, 0, stream>>>(gsum, gcnt, ffnn_W, ffnn_b, out_W, out_b, out);
}

// Round 10
// 308.434 us; speedup vs baseline: 1.0357x; 1.0357x over previous
//
#include <hip/hip_runtime.h>
#include <hip/hip_bf16.h>

#define N_NODES 50000
#define N_EDGES 600000
#define DIM 128
#define N_GRAPHS 64
#define CAP 64            // padded CSR row capacity (mean deg 12; P(deg>=64)~0)
#define CAP_SHIFT 6
#define NPART 8           // node-range partitions (== XCDs under round-robin)
#define PART_SZ (N_NODES / NPART)   // 6250
#define CHUNK 2048        // edges per chunk; each chunk scanned by NPART blocks

typedef __bf16 bf16x8 __attribute__((ext_vector_type(8)));
typedef float f32x4 __attribute__((ext_vector_type(4)));
typedef float f32x2 __attribute__((ext_vector_type(2)));

// round-to-nearest-even fp32 -> bf16 (as ushort)
__device__ __forceinline__ unsigned short f2bf(float f) {
    unsigned int u = __float_as_uint(f);
    u += 0x7FFFu + ((u >> 16) & 1u);
    return (unsigned short)(u >> 16);
}
__device__ __forceinline__ unsigned char f2fp8(float v) {
    return (unsigned char)(__builtin_amdgcn_cvt_pk_fp8_f32(v, v, 0, false) & 0xFF);
}

// ---------------------------------------------------------------------------
// zero accumulators + conv_W -> bf16 transposed WT[l][n][k]
// ---------------------------------------------------------------------------
__global__ __launch_bounds__(256) void zero_wt_kernel(int* __restrict__ deg_out,
                                                      int* __restrict__ cnt_in,
                                                      float* __restrict__ gsum,
                                                      float* __restrict__ gcnt,
                                                      const float* __restrict__ w,
                                                      unsigned short* __restrict__ wt) {
    int i = blockIdx.x * blockDim.x + threadIdx.x;
    if (i < N_NODES) { deg_out[i] = 0; cnt_in[i] = 0; }
    if (i < N_GRAPHS * DIM) gsum[i] = 0.f;
    if (i < N_GRAPHS) gcnt[i] = 0.f;
    if (i < 4 * DIM * DIM) {
        int l = i >> 14;           // layer
        int j = i & 16383;
        int k = j >> 7;
        int n = j & 127;
        wt[(l << 14) + n * DIM + k] = f2bf(w[i]);
    }
}

// ---------------------------------------------------------------------------
// XCD-partitioned CSR build. Each 2048-edge chunk is scanned by NPART blocks;
// block b keeps only nodes in partition (b & 7). Under round-robin dispatch
// b&7 == XCD id, so every slot line / counter line is dirtied by exactly ONE
// XCD L2 -> written back once (WRITE_SIZE 52 MB -> ~8 MB predicted), and
// cnt/deg atomic working set per XCD is 25 KB (no cross-XCD ping-pong).
// Edge list is re-read NPART x (streaming, L3-absorbed). Correctness does
// NOT depend on the XCD mapping -- only locality does.
// ---------------------------------------------------------------------------
__global__ __launch_bounds__(256) void build_kernel(const int* __restrict__ src,
                                                    const int* __restrict__ dst,
                                                    int* __restrict__ deg_out,
                                                    int* __restrict__ cnt_in,
                                                    unsigned short* __restrict__ slots, int ne) {
    int part = blockIdx.x & (NPART - 1);
    int chunk = blockIdx.x >> 3;
    int base = chunk * CHUNK + threadIdx.x * 8;
    int lo = part * PART_SZ;
    int hi = lo + PART_SZ;
    #pragma unroll
    for (int i = 0; i < 8; i += 4) {
        int e = base + i;
        if (e + 3 < ne) {
            int4 s4 = *(const int4*)(src + e);
            int4 d4 = *(const int4*)(dst + e);
            #pragma unroll
            for (int k = 0; k < 4; k++) {
                int s = (&s4.x)[k];
                int d = (&d4.x)[k];
                if (s >= lo && s < hi) atomicAdd(&deg_out[s], 1);
                if (d >= lo && d < hi) {
                    int p = atomicAdd(&cnt_in[d], 1);
                    if (p < CAP) slots[(d << CAP_SHIFT) + p] = (unsigned short)s;
                }
            }
        } else {
            for (int k = 0; k < 4; k++) {
                int ee = e + k;
                if (ee < ne) {
                    int s = src[ee];
                    int d = dst[ee];
                    if (s >= lo && s < hi) atomicAdd(&deg_out[s], 1);
                    if (d >= lo && d < hi) {
                        int p = atomicAdd(&cnt_in[d], 1);
                        if (p < CAP) slots[(d << CAP_SHIFT) + p] = (unsigned short)s;
                    }
                }
            }
        }
    }
}

// ---------------------------------------------------------------------------
// xs(fp8) = e4m3( x * rsqrt(max(deg_out,1)) )   (norm_src computed inline)
// ---------------------------------------------------------------------------
__global__ __launch_bounds__(256) void scale_x_kernel(const float* __restrict__ x,
                                                      const int* __restrict__ deg_out,
                                                      unsigned char* __restrict__ xs) {
    int i = blockIdx.x * blockDim.x + threadIdx.x;     // 8-float chunk index
    if (i >= N_NODES * (DIM / 8)) return;
    int row = i >> 4;                                   // 16 chunks per row
    float ns = __frsqrt_rn(fmaxf((float)deg_out[row], 1.0f));
    const float4* px = (const float4*)(x + (size_t)i * 8);
    float4 v0 = px[0], v1 = px[1];
    unsigned lo = 0, hi = 0;
    lo = __builtin_amdgcn_cvt_pk_fp8_f32(v0.x * ns, v0.y * ns, lo, false);
    lo = __builtin_amdgcn_cvt_pk_fp8_f32(v0.z * ns, v0.w * ns, lo, true);
    hi = __builtin_amdgcn_cvt_pk_fp8_f32(v1.x * ns, v1.y * ns, hi, false);
    hi = __builtin_amdgcn_cvt_pk_fp8_f32(v1.z * ns, v1.w * ns, hi, true);
    uint2 o = {lo, hi};
    *(uint2*)(xs + (size_t)i * 8) = o;
}

// ---------------------------------------------------------------------------
// FUSED conv (round-6 measured form, 313 us config):
// Phase 1 (spmm): wave handles 4 nodes, 16 lanes x 8B per row; hoisted
//   first-chunk index loads + per-node accumulator banks. At the device's
//   scattered-line ceiling (~22 G lines/s) -- parked.
// Phase 2 (gemm): MFMA + epilogue (fp8 store or mean-pool).
// ---------------------------------------------------------------------------
#define LDS_STRIDE 136   // ushorts per row (128 + 8 pad = 272B; 272 % 16 == 0)
__global__ __launch_bounds__(256) void conv_fused_kernel(const int* __restrict__ cnt_in,
                                                         const unsigned short* __restrict__ slots,
                                                         const unsigned char* __restrict__ h8,
                                                         const unsigned short* __restrict__ WT,
                                                         const float* __restrict__ bias,
                                                         unsigned char* __restrict__ C8,
                                                         const int* __restrict__ deg_out,   // non-null: epilogue *rsqrt(deg_out)
                                                         const int* __restrict__ graph_id,  // non-null: pool epilogue
                                                         float* __restrict__ gsum,
                                                         float* __restrict__ gcnt,
                                                         int do_relu) {
    __shared__ unsigned short tileA[16][LDS_STRIDE];
    int wave = threadIdx.x >> 6;
    int lane = threadIdx.x & 63;
    int slot = lane >> 4;          // 0..3: row group within gather instr
    int sub  = lane & 15;          // 8-byte chunk of the 128-byte fp8 row
    int r0 = blockIdx.x * 16;
    int nb = r0 + wave * 4;        // first of this wave's 4 nodes

    // wave-uniform node degrees (one 16B load)
    int4 c4 = *(const int4*)(cnt_in + nb);
    int craw[4], cnt[4];
    #pragma unroll
    for (int nn = 0; nn < 4; nn++) {
        craw[nn] = (&c4.x)[nn];
        cnt[nn] = craw[nn] > CAP ? CAP : craw[nn];
    }

    // hoisted first-chunk index loads: 4 independent loads issued together
    int idx0[4];
    #pragma unroll
    for (int nn = 0; nn < 4; nn++)
        idx0[nn] = (int)slots[((nb + nn) << CAP_SHIFT) + sub];

    const unsigned char* hp = h8 + sub * 8;
    float a[4][8] = {};

    // first chunk (edges 0..15) for ALL 4 nodes: up to 16 loads in flight
    #pragma unroll
    for (int nn = 0; nn < 4; nn++) {
        #pragma unroll
        for (int j = 0; j < 4; j++) {
            int e = slot + 4 * j;
            int s = __shfl(idx0[nn], slot + 4 * j);
            if (e < cnt[nn]) {
                uint2 v = *(const uint2*)(hp + (size_t)s * DIM);
                f32x2 p0 = __builtin_amdgcn_cvt_pk_f32_fp8(v.x, false);
                f32x2 p1 = __builtin_amdgcn_cvt_pk_f32_fp8(v.x, true);
                f32x2 p2 = __builtin_amdgcn_cvt_pk_f32_fp8(v.y, false);
                f32x2 p3 = __builtin_amdgcn_cvt_pk_f32_fp8(v.y, true);
                a[nn][0] += p0[0]; a[nn][1] += p0[1]; a[nn][2] += p1[0]; a[nn][3] += p1[1];
                a[nn][4] += p2[0]; a[nn][5] += p2[1]; a[nn][6] += p3[0]; a[nn][7] += p3[1];
            }
        }
    }

    // residual chunks (deg > 16; wave-uniform branch, ~10% of nodes)
    #pragma unroll
    for (int nn = 0; nn < 4; nn++) {
        for (int base = 16; base < cnt[nn]; base += 16) {
            int idx = (int)slots[((nb + nn) << CAP_SHIFT) + base + sub];
            #pragma unroll
            for (int j = 0; j < 4; j++) {
                int e = base + slot + 4 * j;
                int s = __shfl(idx, slot + 4 * j);
                if (e < cnt[nn]) {
                    uint2 v = *(const uint2*)(hp + (size_t)s * DIM);
                    f32x2 p0 = __builtin_amdgcn_cvt_pk_f32_fp8(v.x, false);
                    f32x2 p1 = __builtin_amdgcn_cvt_pk_f32_fp8(v.x, true);
                    f32x2 p2 = __builtin_amdgcn_cvt_pk_f32_fp8(v.y, false);
                    f32x2 p3 = __builtin_amdgcn_cvt_pk_f32_fp8(v.y, true);
                    a[nn][0] += p0[0]; a[nn][1] += p0[1]; a[nn][2] += p1[0]; a[nn][3] += p1[1];
                    a[nn][4] += p2[0]; a[nn][5] += p2[1]; a[nn][6] += p3[0]; a[nn][7] += p3[1];
                }
            }
        }
    }

    // reduce across the 4 row-groups + store finished bf16 rows (round-0 tree)
    #pragma unroll
    for (int nn = 0; nn < 4; nn++) {
        #pragma unroll
        for (int k = 0; k < 8; k++) {
            a[nn][k] += __shfl_xor(a[nn][k], 16);
            a[nn][k] += __shfl_xor(a[nn][k], 32);
        }
        if (slot == 0) {
            float nd = __frsqrt_rn(fmaxf((float)craw[nn], 1.0f));   // norm_dst inline
            uint4 o;
            o.x = (unsigned)f2bf(a[nn][0] * nd) | ((unsigned)f2bf(a[nn][1] * nd) << 16);
            o.y = (unsigned)f2bf(a[nn][2] * nd) | ((unsigned)f2bf(a[nn][3] * nd) << 16);
            o.z = (unsigned)f2bf(a[nn][4] * nd) | ((unsigned)f2bf(a[nn][5] * nd) << 16);
            o.w = (unsigned)f2bf(a[nn][6] * nd) | ((unsigned)f2bf(a[nn][7] * nd) << 16);
            *(uint4*)&tileA[wave * 4 + nn][sub * 8] = o;
        }
    }
    __syncthreads();

    // ---- phase 2: C[16 x 32-col slice] via MFMA ----
    int quad = lane >> 4;
    int l15 = lane & 15;
    int ct0 = wave * 2;            // two 16-col tiles per wave

    f32x4 acc[2];
    #pragma unroll
    for (int t = 0; t < 2; t++) {
        float bv = bias[(ct0 + t) * 16 + l15];
        acc[t] = (f32x4){bv, bv, bv, bv};
    }

    #pragma unroll
    for (int ks = 0; ks < 4; ks++) {
        bf16x8 af = *(const bf16x8*)&tileA[l15][ks * 32 + quad * 8];
        #pragma unroll
        for (int t = 0; t < 2; t++) {
            bf16x8 bf = *(const bf16x8*)(WT + (size_t)((ct0 + t) * 16 + l15) * DIM + ks * 32 + quad * 8);
            acc[t] = __builtin_amdgcn_mfma_f32_16x16x32_bf16(af, bf, acc[t], 0, 0, 0);
        }
    }

    if (graph_id == nullptr) {
        // conv0..2 epilogue: relu + inline norm_src scale, fp8 store
        #pragma unroll
        for (int reg = 0; reg < 4; reg++) {
            int r = r0 + quad * 4 + reg;
            float rs = __frsqrt_rn(fmaxf((float)deg_out[r], 1.0f));
            #pragma unroll
            for (int t = 0; t < 2; t++) {
                float v = acc[t][reg];
                if (do_relu) v = fmaxf(v, 0.f);
                v *= rs;
                C8[(size_t)r * DIM + (ct0 + t) * 16 + l15] = f2fp8(v);
            }
        }
    } else {
        // conv3 epilogue: mean-pool directly (no C store)
        int g0 = graph_id[r0];
        int g15 = graph_id[r0 + 15];
        if (g0 == g15) {
            // fast path: whole block in one graph
            #pragma unroll
            for (int t = 0; t < 2; t++) {
                float s = acc[t][0] + acc[t][1] + acc[t][2] + acc[t][3];  // 4 rows
                s += __shfl_xor(s, 16);
                s += __shfl_xor(s, 32);        // all 16 rows
                if (quad == 0)
                    atomicAdd(&gsum[g0 * DIM + (ct0 + t) * 16 + l15], s);
            }
            if (threadIdx.x == 0) atomicAdd(&gcnt[g0], 16.0f);
        } else {
            // slow path: per-row atomics (block spans a graph boundary)
            #pragma unroll
            for (int reg = 0; reg < 4; reg++) {
                int r = r0 + quad * 4 + reg;
                int g = graph_id[r];
                #pragma unroll
                for (int t = 0; t < 2; t++)
                    atomicAdd(&gsum[g * DIM + (ct0 + t) * 16 + l15], acc[t][reg]);
            }
            if (threadIdx.x < 16)
                atomicAdd(&gcnt[graph_id[r0 + threadIdx.x]], 1.0f);
        }
    }
}

// ---------------------------------------------------------------------------
// FFNN head: one block per graph (fp32)
// ---------------------------------------------------------------------------
__global__ __launch_bounds__(128) void mlp_kernel(const float* __restrict__ gsum,
                                                  const float* __restrict__ gcnt,
                                                  const float* __restrict__ ffnn_W,
                                                  const float* __restrict__ ffnn_b,
                                                  const float* __restrict__ out_W,
                                                  const float* __restrict__ out_b,
                                                  float* __restrict__ out) {
    __shared__ float buf[DIM];
    __shared__ float red[DIM];
    int g = blockIdx.x;
    int t = threadIdx.x;
    float cnt = fmaxf(gcnt[g], 1.0f);
    buf[t] = gsum[g * DIM + t] / cnt;
    __syncthreads();
    for (int l = 0; l < 3; l++) {
        const float* W = ffnn_W + (size_t)l * DIM * DIM;
        float s = ffnn_b[l * DIM + t];
        for (int k = 0; k < DIM; k++) s += buf[k] * W[k * DIM + t];
        __syncthreads();
        buf[t] = fmaxf(s, 0.0f);
        __syncthreads();
    }
    float p = buf[t] * out_W[t];
    red[t] = p;
    __syncthreads();
    for (int off = 64; off > 0; off >>= 1) {
        if (t < off) red[t] += red[t + off];
        __syncthreads();
    }
    if (t == 0) out[g] = 1.0f / (1.0f + expf(-(red[0] + out_b[0])));
}

// ---------------------------------------------------------------------------
// launch (8 dispatches)
// ---------------------------------------------------------------------------
extern "C" void kernel_launch(void* const* d_in, const int* in_sizes, int n_in,
                              void* d_out, int out_size, void* d_ws, size_t ws_size,
                              hipStream_t stream) {
    const float* x        = (const float*)d_in[0];
    const int*   src      = (const int*)d_in[1];
    const int*   dst      = (const int*)d_in[2];
    const int*   graph_id = (const int*)d_in[3];
    const float* conv_W   = (const float*)d_in[4];
    const float* conv_b   = (const float*)d_in[5];
    const float* ffnn_W   = (const float*)d_in[6];
    const float* ffnn_b   = (const float*)d_in[7];
    const float* out_W    = (const float*)d_in[8];
    const float* out_b    = (const float*)d_in[9];
    float* out = (float*)d_out;

    char* w = (char*)d_ws;
    auto alloc = [&](size_t bytes) -> void* {
        void* p = (void*)w;
        w += (bytes + 255) & ~(size_t)255;
        return p;
    };
    int*            deg_out_i = (int*)alloc(N_NODES * sizeof(int));
    int*            cnt_in    = (int*)alloc(N_NODES * sizeof(int));
    unsigned short* slots     = (unsigned short*)alloc((size_t)N_NODES * CAP * sizeof(unsigned short));
    unsigned char*  h8a  = (unsigned char*)alloc((size_t)N_NODES * DIM);          // fp8 ping
    unsigned char*  h8b  = (unsigned char*)alloc((size_t)N_NODES * DIM);          // fp8 pong
    unsigned short* wbfT = (unsigned short*)alloc(4 * DIM * DIM * sizeof(unsigned short));
    float* gsum      = (float*)alloc(N_GRAPHS * DIM * sizeof(float));
    float* gcnt      = (float*)alloc(N_GRAPHS * sizeof(float));

    // zero + WT transpose (256 blocks to cover 4*128*128 = 65536)
    zero_wt_kernel<<<(4 * DIM * DIM + 255) / 256, 256, 0, stream>>>(deg_out_i, cnt_in, gsum, gcnt, conv_W, wbfT);
    // XCD-partitioned build: 8 blocks per 2048-edge chunk
    {
        int nchunk = (N_EDGES + CHUNK - 1) / CHUNK;   // 293
        build_kernel<<<nchunk * NPART, 256, 0, stream>>>(src, dst, deg_out_i, cnt_in, slots, N_EDGES);
    }
    scale_x_kernel<<<(N_NODES * (DIM / 8) + 255) / 256, 256, 0, stream>>>(x, deg_out_i, h8a);

    const int conv_blocks = N_NODES / 16;   // 3125

    // conv0..2: fused spmm+gemm, fp8 out (relu + inline norm_src)
    conv_fused_kernel<<<conv_blocks, 256, 0, stream>>>(cnt_in, slots, h8a,
        wbfT + 0 * DIM * DIM, conv_b + 0 * DIM, h8b, deg_out_i,
        (const int*)nullptr, (float*)nullptr, (float*)nullptr, 1);
    conv_fused_kernel<<<conv_blocks, 256, 0, stream>>>(cnt_in, slots, h8b,
        wbfT + 1 * DIM * DIM, conv_b + 1 * DIM, h8a, deg_out_i,
        (const int*)nullptr, (float*)nullptr, (float*)nullptr, 1);
    conv_fused_kernel<<<conv_blocks, 256, 0, stream>>>(cnt_in, slots, h8a,
        wbfT + 2 * DIM * DIM, conv_b + 2 * DIM, h8b, deg_out_i,
        (const int*)nullptr, (float*)nullptr, (float*)nullptr, 1);
    // conv3: no relu, no scale, pooled epilogue (no C store)
    conv_fused_kernel<<<conv_blocks, 256, 0, stream>>>(cnt_in, slots, h8b,
        wbfT + 3 * DIM * DIM, conv_b + 3 * DIM, (unsigned char*)nullptr, (const int*)nullptr,
        graph_id, gsum, gcnt, 0);

    // head
    mlp_kernel<<<N_GRAPHS, 128, 0, stream>>>(gsum, gcnt, ffnn_W, ffnn_b, out_W, out_b, out);
}